// Round 2
// baseline (645.796 us; speedup 1.0000x reference)
//
#include <hip/hip_runtime.h>
#include <hip/hip_bf16.h>

// B=4, S=2048, H=1024, heads=16, d=64
// out: [8192][1024] f32, then avg_attn: [4][2048][2048] f32
// ws: Qb bf16[8192][1024], Kb bf16[8192][1024], Vt bf16[4][64][2048], AOb bf16[8192][64]

typedef float f32x4 __attribute__((ext_vector_type(4)));
typedef short s16x8 __attribute__((ext_vector_type(8)));

#define DEVI static __device__ __forceinline__
#define MFMA16(a, b, c) __builtin_amdgcn_mfma_f32_16x16x32_bf16(a, b, c, 0, 0, 0)

DEVI unsigned short f2bf(float f) {
  union { float f; unsigned u; } v; v.f = f;
  return (unsigned short)((v.u + 0x7fffu + ((v.u >> 16) & 1u)) >> 16);
}

DEVI s16x8 pack2(f32x4 lo, f32x4 hi) {
  s16x8 r;
  r[0] = (short)f2bf(lo[0]); r[1] = (short)f2bf(lo[1]);
  r[2] = (short)f2bf(lo[2]); r[3] = (short)f2bf(lo[3]);
  r[4] = (short)f2bf(hi[0]); r[5] = (short)f2bf(hi[1]);
  r[6] = (short)f2bf(hi[2]); r[7] = (short)f2bf(hi[3]);
  return r;
}

DEVI float fast_exp2(float x) {
#if __has_builtin(__builtin_amdgcn_exp2f)
  return __builtin_amdgcn_exp2f(x);
#else
  return exp2f(x);
#endif
}

// ---------------- Kernel 1: Q and K projections (z=0 -> Q, z=1 -> K) -------
// C[m,n] = sum_k A[m,k]*W[n,k] + bias[n], stored bf16. 128x128 tile, BK=32.
__global__ __launch_bounds__(256, 2) void proj_qk(
    const float* __restrict__ q_in, const float* __restrict__ k_in,
    const float* __restrict__ Wq, const float* __restrict__ Wk,
    const float* __restrict__ bq, const float* __restrict__ bk,
    unsigned short* __restrict__ Qb, unsigned short* __restrict__ Kb) {
  const float* A = blockIdx.z ? k_in : q_in;
  const float* Bw = blockIdx.z ? Wk : Wq;
  const float* bias = blockIdx.z ? bk : bq;
  unsigned short* C = blockIdx.z ? Kb : Qb;

  __shared__ short As[128][32];
  __shared__ short Bs[128][32];

  const int t = threadIdx.x;
  const int lane = t & 63, wid = t >> 6;
  const int wm = wid >> 1, wn = wid & 1;
  const int fr = lane & 15, g = lane >> 4;
  const int m0 = blockIdx.x * 128, n0 = blockIdx.y * 128;

  const int sr = t >> 1, sc = (t & 1) * 16;
  const float* Ap = A + (size_t)(m0 + sr) * 1024 + sc;
  const float* Bp = Bw + (size_t)(n0 + sr) * 1024 + sc;

  f32x4 acc[4][4];
#pragma unroll
  for (int i = 0; i < 4; ++i)
#pragma unroll
    for (int j = 0; j < 4; ++j) acc[i][j] = (f32x4){0.f, 0.f, 0.f, 0.f};

  for (int kt = 0; kt < 32; ++kt) {
    const f32x4 ar0 = *(const f32x4*)(Ap + 0), ar1 = *(const f32x4*)(Ap + 4),
                ar2 = *(const f32x4*)(Ap + 8), ar3 = *(const f32x4*)(Ap + 12);
    const f32x4 br0 = *(const f32x4*)(Bp + 0), br1 = *(const f32x4*)(Bp + 4),
                br2 = *(const f32x4*)(Bp + 8), br3 = *(const f32x4*)(Bp + 12);
    Ap += 32; Bp += 32;
    __syncthreads();  // previous tile's compute done
    *(s16x8*)&As[sr][sc] = pack2(ar0, ar1);
    *(s16x8*)&As[sr][sc + 8] = pack2(ar2, ar3);
    *(s16x8*)&Bs[sr][sc] = pack2(br0, br1);
    *(s16x8*)&Bs[sr][sc + 8] = pack2(br2, br3);
    __syncthreads();

    s16x8 af[4], bf[4];
#pragma unroll
    for (int mt = 0; mt < 4; ++mt) af[mt] = *(const s16x8*)&As[wm * 64 + mt * 16 + fr][g * 8];
#pragma unroll
    for (int nt = 0; nt < 4; ++nt) bf[nt] = *(const s16x8*)&Bs[wn * 64 + nt * 16 + fr][g * 8];
#pragma unroll
    for (int mt = 0; mt < 4; ++mt)
#pragma unroll
      for (int nt = 0; nt < 4; ++nt)
        acc[mt][nt] = MFMA16(af[mt], bf[nt], acc[mt][nt]);
  }

#pragma unroll
  for (int nt = 0; nt < 4; ++nt) {
    const int col = n0 + wn * 64 + nt * 16 + fr;
    const float bb = bias[col];
#pragma unroll
    for (int mt = 0; mt < 4; ++mt) {
      const int row = m0 + wm * 64 + mt * 16 + g * 4;
#pragma unroll
      for (int r = 0; r < 4; ++r)
        C[(size_t)(row + r) * 1024 + col] = f2bf(acc[mt][nt][r] + bb);
    }
  }
}

// ---------------- Kernel 2: V projection, stored TRANSPOSED Vt[b][d][s] ----
__global__ __launch_bounds__(256, 2) void proj_v(
    const float* __restrict__ val, const float* __restrict__ Wv,
    const float* __restrict__ bv, unsigned short* __restrict__ Vt) {
  __shared__ short As[64][32];
  __shared__ short Bs[64][32];
  const int t = threadIdx.x, lane = t & 63, w = t >> 6;
  const int fr = lane & 15, g = lane >> 4;
  const int m0 = blockIdx.x * 64;
  const int sr = t >> 2, sc = (t & 3) * 8;
  const float* Ap = val + (size_t)(m0 + sr) * 1024 + sc;
  const float* Bp = Wv + (size_t)sr * 1024 + sc;

  f32x4 acc[4];
#pragma unroll
  for (int i = 0; i < 4; ++i) acc[i] = (f32x4){0.f, 0.f, 0.f, 0.f};

  for (int kt = 0; kt < 32; ++kt) {
    const f32x4 a0 = *(const f32x4*)Ap, a1 = *(const f32x4*)(Ap + 4);
    const f32x4 b0 = *(const f32x4*)Bp, b1 = *(const f32x4*)(Bp + 4);
    Ap += 32; Bp += 32;
    __syncthreads();
    *(s16x8*)&As[sr][sc] = pack2(a0, a1);
    *(s16x8*)&Bs[sr][sc] = pack2(b0, b1);
    __syncthreads();
    const s16x8 a = *(const s16x8*)&As[w * 16 + fr][g * 8];
#pragma unroll
    for (int nt = 0; nt < 4; ++nt) {
      const s16x8 b = *(const s16x8*)&Bs[nt * 16 + fr][g * 8];
      acc[nt] = MFMA16(a, b, acc[nt]);
    }
  }
#pragma unroll
  for (int nt = 0; nt < 4; ++nt) {
    const int d = nt * 16 + fr;
    const float bb = bv[d];
#pragma unroll
    for (int r = 0; r < 4; ++r) {
      const int srow = m0 + w * 16 + g * 4 + r;
      Vt[((size_t)(srow >> 11) * 64 + d) * 2048 + (srow & 2047)] = f2bf(acc[nt][r] + bb);
    }
  }
}

// ---------------- Kernel 3: fused scores -> softmax -> head-avg -----------
// One block = (batch, 16 q-rows). 8 waves, each owns 256 keys.
// Per head: score tile in regs (64 f32/lane), 16-lane shfl + LDS cross-wave
// reduce for max/sum, accumulate avg (64 f32/lane), write avg_attn once.
__global__ __launch_bounds__(512, 2) void attn_avg(
    const unsigned short* __restrict__ Qb, const unsigned short* __restrict__ Kb,
    float* __restrict__ avg_out) {
  __shared__ short Qs[16 * 1024];
  __shared__ float redm[16][8];
  __shared__ float redl[16][8];

  const int t = threadIdx.x, lane = t & 63, w = t >> 6;
  const int fr = lane & 15, g = lane >> 4;
  int bx = blockIdx.x;
  bx = (bx & 7) * 64 + (bx >> 3);  // XCD-contiguous swizzle (512 = 8*64)
  const int b = bx >> 7, q0 = (bx & 127) << 4;

  const unsigned short* Qrow = Qb + (size_t)(b * 2048 + q0) * 1024;
#pragma unroll
  for (int j = 0; j < 4; ++j) {
    const int c = t + 512 * j;
    *(s16x8*)(Qs + c * 8) = *(const s16x8*)(Qrow + c * 8);
  }
  __syncthreads();

  float avg[16][4];
#pragma unroll
  for (int kt = 0; kt < 16; ++kt)
#pragma unroll
    for (int r = 0; r < 4; ++r) avg[kt][r] = 0.f;

  const float cs = 0.125f * 1.44269504088896340736f;  // scale * log2(e)
  const unsigned short* Kbase = Kb + (size_t)(b * 2048 + w * 256) * 1024;

  for (int h = 0; h < 16; ++h) {
    const s16x8 a0 = *(const s16x8*)&Qs[fr * 1024 + h * 64 + g * 8];
    const s16x8 a1 = *(const s16x8*)&Qs[fr * 1024 + h * 64 + 32 + g * 8];
    float s[16][4];
    float mx[4] = {-3.0e38f, -3.0e38f, -3.0e38f, -3.0e38f};
#pragma unroll
    for (int kt = 0; kt < 16; ++kt) {
      const unsigned short* kp = Kbase + (size_t)(kt * 16 + fr) * 1024 + h * 64 + g * 8;
      const s16x8 b0 = *(const s16x8*)kp;
      const s16x8 b1 = *(const s16x8*)(kp + 32);
      f32x4 sc = (f32x4){0.f, 0.f, 0.f, 0.f};
      sc = MFMA16(a0, b0, sc);
      sc = MFMA16(a1, b1, sc);
#pragma unroll
      for (int r = 0; r < 4; ++r) { s[kt][r] = sc[r]; mx[r] = fmaxf(mx[r], sc[r]); }
    }
    // row max across the 16 key-columns of this lane-group
#pragma unroll
    for (int d = 1; d < 16; d <<= 1)
#pragma unroll
      for (int r = 0; r < 4; ++r) mx[r] = fmaxf(mx[r], __shfl_xor(mx[r], d));
    if (fr == 0) {
#pragma unroll
      for (int r = 0; r < 4; ++r) redm[g * 4 + r][w] = mx[r];
    }
    __syncthreads();
    float mc[4], lsum[4];
#pragma unroll
    for (int r = 0; r < 4; ++r) {
      const f32x4 p0 = *(const f32x4*)&redm[g * 4 + r][0];
      const f32x4 p1 = *(const f32x4*)&redm[g * 4 + r][4];
      const float m8 = fmaxf(fmaxf(fmaxf(p0[0], p0[1]), fmaxf(p0[2], p0[3])),
                             fmaxf(fmaxf(p1[0], p1[1]), fmaxf(p1[2], p1[3])));
      mc[r] = m8 * cs;
      lsum[r] = 0.f;
    }
#pragma unroll
    for (int kt = 0; kt < 16; ++kt)
#pragma unroll
      for (int r = 0; r < 4; ++r) {
        const float e = fast_exp2(s[kt][r] * cs - mc[r]);
        s[kt][r] = e;
        lsum[r] += e;
      }
#pragma unroll
    for (int d = 1; d < 16; d <<= 1)
#pragma unroll
      for (int r = 0; r < 4; ++r) lsum[r] += __shfl_xor(lsum[r], d);
    if (fr == 0) {
#pragma unroll
      for (int r = 0; r < 4; ++r) redl[g * 4 + r][w] = lsum[r];
    }
    __syncthreads();
    float inv[4];
#pragma unroll
    for (int r = 0; r < 4; ++r) {
      const f32x4 p0 = *(const f32x4*)&redl[g * 4 + r][0];
      const f32x4 p1 = *(const f32x4*)&redl[g * 4 + r][4];
      const float lt = ((p0[0] + p0[1]) + (p0[2] + p0[3])) + ((p1[0] + p1[1]) + (p1[2] + p1[3]));
      inv[r] = 1.0f / (16.0f * lt);
    }
#pragma unroll
    for (int kt = 0; kt < 16; ++kt)
#pragma unroll
      for (int r = 0; r < 4; ++r) avg[kt][r] += s[kt][r] * inv[r];
  }

  float* orow = avg_out + (size_t)(b * 2048 + q0 + g * 4) * 2048 + w * 256 + fr;
#pragma unroll
  for (int kt = 0; kt < 16; ++kt)
#pragma unroll
    for (int r = 0; r < 4; ++r)
      orow[(size_t)r * 2048 + kt * 16] = avg[kt][r];
}

// ---------------- Kernel 4: attn_out = avg_attn @ V  (bf16 out) -----------
__global__ __launch_bounds__(256, 2) void pv_out(
    const float* __restrict__ avg, const unsigned short* __restrict__ Vt,
    unsigned short* __restrict__ AOb) {
  const int t = threadIdx.x, lane = t & 63, w = t >> 6;
  const int fr = lane & 15, g = lane >> 4;
  const int bx = blockIdx.x;
  const int b = bx >> 5, q0 = (bx & 31) * 64;
  const float* ap = avg + (size_t)(b * 2048 + q0 + w * 16 + fr) * 2048 + g * 8;
  const unsigned short* vp = Vt + ((size_t)b * 64 + fr) * 2048 + g * 8;
  f32x4 acc[4];
#pragma unroll
  for (int i = 0; i < 4; ++i) acc[i] = (f32x4){0.f, 0.f, 0.f, 0.f};
  for (int kt = 0; kt < 64; ++kt) {
    const f32x4 alo = *(const f32x4*)(ap + kt * 32);
    const f32x4 ahi = *(const f32x4*)(ap + kt * 32 + 4);
    const s16x8 a = pack2(alo, ahi);
#pragma unroll
    for (int nt = 0; nt < 4; ++nt) {
      const s16x8 bfr = *(const s16x8*)(vp + (size_t)nt * 16 * 2048 + kt * 32);
      acc[nt] = MFMA16(a, bfr, acc[nt]);
    }
  }
#pragma unroll
  for (int nt = 0; nt < 4; ++nt) {
    const int d = nt * 16 + fr;
#pragma unroll
    for (int r = 0; r < 4; ++r)
      AOb[(size_t)(b * 2048 + q0 + w * 16 + g * 4 + r) * 64 + d] = f2bf(acc[nt][r]);
  }
}

// ---------------- Kernel 5: output = attn_out @ Wo^T + bo (f32 out) -------
__global__ __launch_bounds__(256, 2) void proj_o(
    const unsigned short* __restrict__ AOb, const float* __restrict__ Wo,
    const float* __restrict__ bo, float* __restrict__ out) {
  const int t = threadIdx.x, lane = t & 63, wid = t >> 6;
  const int wm = wid >> 1, wn = wid & 1;
  const int fr = lane & 15, g = lane >> 4;
  const int m0 = blockIdx.x * 128, n0 = blockIdx.y * 128;
  f32x4 acc[4][4];
#pragma unroll
  for (int i = 0; i < 4; ++i)
#pragma unroll
    for (int j = 0; j < 4; ++j) acc[i][j] = (f32x4){0.f, 0.f, 0.f, 0.f};
#pragma unroll
  for (int ks = 0; ks < 2; ++ks) {
    s16x8 af[4], bf[4];
#pragma unroll
    for (int mt = 0; mt < 4; ++mt)
      af[mt] = *(const s16x8*)(AOb + (size_t)(m0 + wm * 64 + mt * 16 + fr) * 64 + ks * 32 + g * 8);
#pragma unroll
    for (int nt = 0; nt < 4; ++nt) {
      const float* wp = Wo + (size_t)(n0 + wn * 64 + nt * 16 + fr) * 64 + ks * 32 + g * 8;
      bf[nt] = pack2(*(const f32x4*)wp, *(const f32x4*)(wp + 4));
    }
#pragma unroll
    for (int mt = 0; mt < 4; ++mt)
#pragma unroll
      for (int nt = 0; nt < 4; ++nt)
        acc[mt][nt] = MFMA16(af[mt], bf[nt], acc[mt][nt]);
  }
#pragma unroll
  for (int nt = 0; nt < 4; ++nt) {
    const int col = n0 + wn * 64 + nt * 16 + fr;
    const float bb = bo[col];
#pragma unroll
    for (int mt = 0; mt < 4; ++mt) {
      const int row = m0 + wm * 64 + mt * 16 + g * 4;
#pragma unroll
      for (int r = 0; r < 4; ++r)
        out[(size_t)(row + r) * 1024 + col] = acc[mt][nt][r] + bb;
    }
  }
}

extern "C" void kernel_launch(void* const* d_in, const int* in_sizes, int n_in,
                              void* d_out, int out_size, void* d_ws, size_t ws_size,
                              hipStream_t stream) {
  const float* query = (const float*)d_in[0];
  const float* key_in = (const float*)d_in[1];
  const float* value = (const float*)d_in[2];
  const float* Wq = (const float*)d_in[3];
  const float* bq = (const float*)d_in[4];
  const float* Wk = (const float*)d_in[5];
  const float* bk = (const float*)d_in[6];
  const float* Wv = (const float*)d_in[7];
  const float* bv = (const float*)d_in[8];
  const float* Wo = (const float*)d_in[9];
  const float* bo = (const float*)d_in[10];

  unsigned short* Qb = (unsigned short*)d_ws;
  unsigned short* Kb = Qb + 8388608;
  unsigned short* Vt = Kb + 8388608;
  unsigned short* AOb = Vt + 524288;

  float* out = (float*)d_out;
  float* avg_out = out + 8388608;

  hipLaunchKernelGGL(proj_qk, dim3(64, 8, 2), dim3(256), 0, stream,
                     query, key_in, Wq, Wk, bq, bk, Qb, Kb);
  hipLaunchKernelGGL(proj_v, dim3(128), dim3(256), 0, stream, value, Wv, bv, Vt);
  hipLaunchKernelGGL(attn_avg, dim3(512), dim3(512), 0, stream, Qb, Kb, avg_out);
  hipLaunchKernelGGL(pv_out, dim3(128), dim3(256), 0, stream, avg_out, Vt, AOb);
  hipLaunchKernelGGL(proj_o, dim3(64, 8), dim3(256), 0, stream, AOb, Wo, bo, out);
}